// Round 1
// 383.997 us; speedup vs baseline: 1.0892x; 1.0892x over previous
//
#include <hip/hip_runtime.h>

static __device__ inline float b2f(unsigned short u){
  union { unsigned int i; float f; } v; v.i = ((unsigned int)u) << 16; return v.f;
}
static __device__ inline unsigned short f2b(float f){
  union { float ff; unsigned int u; } v; v.ff = f;
  unsigned int xx = v.u;
  return (unsigned short)((xx + 0x7fffu + ((xx >> 16) & 1u)) >> 16);
}

typedef __attribute__((ext_vector_type(8))) short short8x;   // 8 bf16 (4 VGPRs)
typedef __attribute__((ext_vector_type(4))) float f32x4;

// fp32 inputs/output (verified r13); internal staging bf16 (verified 4.9e-4).

__global__ __launch_bounds__(256) void CarbonGNN_36447092474498_init(
    int* __restrict__ cnt, int* __restrict__ cursor, int N){
  int i = blockIdx.x * 256 + threadIdx.x;
  if (i < N){ cnt[i] = 0; cursor[i] = 0; }
}

__global__ __launch_bounds__(256) void CarbonGNN_36447092474498_hist(
    const int* __restrict__ dst, int E, int* __restrict__ cnt){
  int e = blockIdx.x * 256 + threadIdx.x;
  if (e < E) atomicAdd(&cnt[dst[e]], 1);
}

__global__ __launch_bounds__(256) void CarbonGNN_36447092474498_scan1(
    const int* __restrict__ cnt, int n, int* __restrict__ excl, int* __restrict__ bsum){
  __shared__ int sm[256];
  int t = threadIdx.x;
  int i = blockIdx.x * 256 + t;
  int v = (i < n) ? cnt[i] : 0;
  sm[t] = v;
  __syncthreads();
  for (int ofs = 1; ofs < 256; ofs <<= 1){
    int y = (t >= ofs) ? sm[t - ofs] : 0;
    __syncthreads();
    sm[t] += y;
    __syncthreads();
  }
  if (i < n) excl[i] = sm[t] - v;
  if (t == 255) bsum[blockIdx.x] = sm[t];
}

// scan2 merged in: every block redundantly scans the <=256 block sums.
__global__ __launch_bounds__(256) void CarbonGNN_36447092474498_scan3(
    const int* __restrict__ excl, const int* __restrict__ bsum, int nb,
    const int* __restrict__ cnt, int n, int E,
    int* __restrict__ off, float* __restrict__ dinv){
  __shared__ int sm[256];
  int t = threadIdx.x;
  int v = (t < nb) ? bsum[t] : 0;
  sm[t] = v;
  __syncthreads();
  for (int ofs = 1; ofs < 256; ofs <<= 1){
    int y = (t >= ofs) ? sm[t - ofs] : 0;
    __syncthreads();
    sm[t] += y;
    __syncthreads();
  }
  int bofs = (blockIdx.x == 0) ? 0 : sm[blockIdx.x - 1];
  int i = blockIdx.x * 256 + t;
  if (i < n){
    off[i] = excl[i] + bofs;
    int c = cnt[i];
    dinv[i] = (c >= 0 && c <= E) ? rsqrtf((float)(c + 1)) : 1.0f;
  }
  if (i == 0) off[n] = E;
}

__global__ __launch_bounds__(256) void CarbonGNN_36447092474498_fill(
    const int* __restrict__ src, const int* __restrict__ dst, int E,
    const int* __restrict__ off, int* __restrict__ cursor, int* __restrict__ csr){
  int e = blockIdx.x * 256 + threadIdx.x;
  if (e < E){
    int d = dst[e];
    int p = atomicAdd(&cursor[d], 1);
    csr[off[d] + p] = src[e];
  }
}

// xw[N,64] = x[N,128] @ Wg[128,64]; wave per node, lane = col; Wg in LDS
__global__ __launch_bounds__(256) void CarbonGNN_36447092474498_gemm1(
    const float* __restrict__ x, const float* __restrict__ Wg,
    unsigned short* __restrict__ xw, int N){
  __shared__ float ws[128 * 64];
  int t = threadIdx.x;
  for (int i = t; i < 8192; i += 256) ws[i] = Wg[i];
  __syncthreads();
  int node = blockIdx.x * 4 + (t >> 6);
  if (node >= N) return;
  int c = t & 63;
  const float* ar = x + (size_t)node * 128;
  float acc = 0.f;
  for (int k = 0; k < 128; k += 4){
    float4 xv = *(const float4*)(ar + k);
    acc = fmaf(xv.x, ws[(k + 0) * 64 + c], acc);
    acc = fmaf(xv.y, ws[(k + 1) * 64 + c], acc);
    acc = fmaf(xv.z, ws[(k + 2) * 64 + c], acc);
    acc = fmaf(xv.w, ws[(k + 3) * 64 + c], acc);
  }
  xw[(size_t)node * 64 + c] = f2b(acc);
}

// GCN aggregate: wave per node, lane = channel; 4-edge unrolled
__global__ __launch_bounds__(256) void CarbonGNN_36447092474498_gcn(
    const unsigned short* __restrict__ xw, const int* __restrict__ off,
    const int* __restrict__ csr, const float* __restrict__ dinv,
    const float* __restrict__ bgcn, unsigned short* __restrict__ h, int N){
  int node = blockIdx.x * 4 + (threadIdx.x >> 6);
  if (node >= N) return;
  int c = threadIdx.x & 63;
  float di = dinv[node];
  float o = b2f(xw[(size_t)node * 64 + c]) * di;
  int k0 = off[node], k1 = off[node + 1];
  int k = k0;
  for (; k + 3 < k1; k += 4){
    int s0 = csr[k], s1 = csr[k + 1], s2 = csr[k + 2], s3 = csr[k + 3];
    float v0 = b2f(xw[(size_t)s0 * 64 + c]);
    float v1 = b2f(xw[(size_t)s1 * 64 + c]);
    float v2 = b2f(xw[(size_t)s2 * 64 + c]);
    float v3 = b2f(xw[(size_t)s3 * 64 + c]);
    float d0 = dinv[s0], d1 = dinv[s1], d2 = dinv[s2], d3 = dinv[s3];
    o = fmaf(v0, d0, o); o = fmaf(v1, d1, o);
    o = fmaf(v2, d2, o); o = fmaf(v3, d3, o);
  }
  for (; k < k1; k++){
    int s = csr[k];
    o = fmaf(b2f(xw[(size_t)s * 64 + c]), dinv[s], o);
  }
  float val = fmaxf(fmaf(o, di, bgcn[c]), 0.f);
  h[(size_t)node * 64 + c] = f2b(val);
}

// Pre-pack W^T = [Wl|Wr]^T into MFMA A-fragment lane order, split into
// bf16 hi + bf16 lo (residual) so h @ (hi+lo) keeps ~fp32 weight precision.
// Layout: frag block fb = ct*4 + kt*2 + p (ct=col-tile of 16, kt=K-tile of 32,
// p=0 hi / p=1 lo); element fb*512 + lane*8 + i, with
//   value = bf16part( W[k = kt*32 + (lane>>4)*8 + i][c = ct*16 + (lane&15)] ).
__global__ __launch_bounds__(256) void CarbonGNN_36447092474498_wpack(
    const float* __restrict__ Wl, const float* __restrict__ Wr,
    unsigned short* __restrict__ wp){
  int idx = blockIdx.x * 256 + threadIdx.x;       // 0..65535
  int i    = idx & 7;
  int lane = (idx >> 3) & 63;
  int p    = (idx >> 9) & 1;
  int kt   = (idx >> 10) & 1;
  int ct   = idx >> 11;                            // 0..31
  int c = ct * 16 + (lane & 15);
  int k = kt * 32 + (lane >> 4) * 8 + i;
  float w = (c < 256) ? Wl[k * 256 + c] : Wr[k * 256 + (c - 256)];
  unsigned short hi = f2b(w);
  unsigned short out = p ? f2b(w - b2f(hi)) : hi;
  int fb = ct * 4 + kt * 2 + p;
  wp[(size_t)fb * 512 + lane * 8 + i] = out;
}

// gemm2 (MFMA): xlr[N,512] = h[N,64] @ [Wl|Wr][64,512] + b, bf16 out, plus
// S[n][side*4+head] = att_head . rounded(x_side[n, head*64 .. +63]).
// Computes the TRANSPOSED product D' = W^T . h^T with 16x16x32 bf16 MFMA so
// the C layout (col=lane&15=node-row, row=(lane>>4)*4+reg=out-col) gives each
// lane 4 consecutive output cols of one node -> uint2 vector stores.
// Wave = 32 rows (2 row-tiles); block = 4 waves = 128 rows; grid.y = col side.
// No LDS. W frags prefetched one ct ahead; W stays L2-resident (128 KB).
__global__ __launch_bounds__(256) void CarbonGNN_36447092474498_gemm2(
    const unsigned short* __restrict__ h, const unsigned short* __restrict__ wp,
    const float* __restrict__ bl, const float* __restrict__ br,
    const float* __restrict__ attw,
    unsigned short* __restrict__ xlr, float* __restrict__ S, int N){
  int t = threadIdx.x;
  int lane = t & 63;
  int l15 = lane & 15;
  int lg = lane >> 4;
  int r0 = blockIdx.x * 128 + (t >> 6) * 32;
  int side = blockIdx.y;                 // 0: xl cols 0..255, 1: xr cols 256..511

  // B-operand (h^T) fragments: lane needs h[row = r0+rt*16+(lane&15)][k], 8
  // contiguous bf16 per K-tile -> one 16B load each. Clamp OOB rows (stores
  // are guarded; MFMA columns are independent so garbage can't leak).
  short8x bfr[2][2];
  #pragma unroll
  for (int rt = 0; rt < 2; rt++){
    int row = r0 + rt * 16 + l15;
    int rc = row < N ? row : (N - 1);
    const unsigned short* hp = h + (size_t)rc * 64 + lg * 8;
    bfr[rt][0] = *(const short8x*)(hp);
    bfr[rt][1] = *(const short8x*)(hp + 32);
  }

  const unsigned short* wpp = wp + (size_t)(side * 16) * 2048 + (size_t)lane * 8;
  short8x ah0 = *(const short8x*)(wpp);
  short8x al0 = *(const short8x*)(wpp + 512);
  short8x ah1 = *(const short8x*)(wpp + 1024);
  short8x al1 = *(const short8x*)(wpp + 1536);

  float sp0 = 0.f, sp1 = 0.f;           // S partials (per-lane cols) per row-tile
  for (int cl = 0; cl < 16; cl++){
    short8x ch0 = ah0, cg0 = al0, ch1 = ah1, cg1 = al1;
    if (cl < 15){
      const unsigned short* np = wpp + (size_t)(cl + 1) * 2048;
      ah0 = *(const short8x*)(np);
      al0 = *(const short8x*)(np + 512);
      ah1 = *(const short8x*)(np + 1024);
      al1 = *(const short8x*)(np + 1536);
    }
    int c4 = (side * 16 + cl) * 16 + lg * 4;   // first of this lane's 4 out cols
    float4 bias = (c4 < 256) ? *(const float4*)(bl + c4)
                             : *(const float4*)(br + (c4 - 256));
    float4 aw = *(const float4*)(attw + (c4 & 255));
    #pragma unroll
    for (int rt = 0; rt < 2; rt++){
      f32x4 acc = {0.f, 0.f, 0.f, 0.f};
      acc = __builtin_amdgcn_mfma_f32_16x16x32_bf16(ch0, bfr[rt][0], acc, 0, 0, 0);
      acc = __builtin_amdgcn_mfma_f32_16x16x32_bf16(cg0, bfr[rt][0], acc, 0, 0, 0);
      acc = __builtin_amdgcn_mfma_f32_16x16x32_bf16(ch1, bfr[rt][1], acc, 0, 0, 0);
      acc = __builtin_amdgcn_mfma_f32_16x16x32_bf16(cg1, bfr[rt][1], acc, 0, 0, 0);
      float v0 = acc[0] + bias.x;
      float v1 = acc[1] + bias.y;
      float v2 = acc[2] + bias.z;
      float v3 = acc[3] + bias.w;
      unsigned int p01, p23;                    // RNE pack, matches f2b
      asm("v_cvt_pk_bf16_f32 %0, %1, %2" : "=v"(p01) : "v"(v0), "v"(v1));
      asm("v_cvt_pk_bf16_f32 %0, %1, %2" : "=v"(p23) : "v"(v2), "v"(v3));
      int row = r0 + rt * 16 + l15;
      if (row < N){
        uint2 pv; pv.x = p01; pv.y = p23;
        *(uint2*)(xlr + (size_t)row * 512 + c4) = pv;
      }
      // S from the SAME rounded bf16 values GAT will read
      union { unsigned int u; float f; } q0, q1, q2, q3;
      q0.u = p01 << 16; q1.u = p01 & 0xffff0000u;
      q2.u = p23 << 16; q3.u = p23 & 0xffff0000u;
      float s = fmaf(aw.x, q0.f, fmaf(aw.y, q1.f, fmaf(aw.z, q2.f, aw.w * q3.f)));
      if (rt == 0) sp0 += s; else sp1 += s;
    }
    if ((cl & 3) == 3){                          // head boundary (64 cols)
      int head = cl >> 2;
      float s0 = sp0, s1 = sp1;
      s0 += __shfl_xor(s0, 16, 64); s0 += __shfl_xor(s0, 32, 64);
      s1 += __shfl_xor(s1, 16, 64); s1 += __shfl_xor(s1, 32, 64);
      if (lane < 16){
        int ra = r0 + l15;
        if (ra < N) S[(size_t)ra * 8 + side * 4 + head] = s0;
        int rb = r0 + 16 + l15;
        if (rb < N) S[(size_t)rb * 8 + side * 4 + head] = s1;
      }
      sp0 = 0.f; sp1 = 0.f;
    }
  }
}

// GATv2: anchored-softmax (anchor = self logit), lrelu decomposed via S.
// logit_e = 0.6*(Sl[s]+Sr[d]) + 0.4 * att.|xl[s]+xr[d]|
__global__ __launch_bounds__(256) void CarbonGNN_36447092474498_kernel(
    const unsigned short* __restrict__ xlr, const int* __restrict__ off,
    const int* __restrict__ csr, const float* __restrict__ attw,
    const float* __restrict__ S,
    const float* __restrict__ bgat, const float* __restrict__ wlin,
    const float* __restrict__ blin, float* __restrict__ out, int N){
  int node = blockIdx.x * 4 + (threadIdx.x >> 6);
  if (node >= N) return;
  int lane = threadIdx.x & 63;
  int c4 = lane * 4;
  int l = lane & 15;
  int hd = lane >> 4;
  const unsigned short* xrow = xlr + (size_t)node * 512;

  ushort4 xr4 = *(const ushort4*)(xrow + 256 + c4);
  float xr0 = b2f(xr4.x), xr1 = b2f(xr4.y), xr2 = b2f(xr4.z), xr3 = b2f(xr4.w);
  float aw0 = attw[c4 + 0], aw1 = attw[c4 + 1];
  float aw2 = attw[c4 + 2], aw3 = attw[c4 + 3];
  float Sr06 = 0.6f * S[(size_t)node * 8 + 4 + hd];

  // self edge: anchor
  ushort4 xs4 = *(const ushort4*)(xrow + c4);
  float x0 = b2f(xs4.x), x1 = b2f(xs4.y), x2 = b2f(xs4.z), x3 = b2f(xs4.w);
  float R = aw0 * fabsf(x0 + xr0);
  R = fmaf(aw1, fabsf(x1 + xr1), R);
  R = fmaf(aw2, fabsf(x2 + xr2), R);
  R = fmaf(aw3, fabsf(x3 + xr3), R);
  R += __shfl_xor(R, 1, 64); R += __shfl_xor(R, 2, 64);
  R += __shfl_xor(R, 4, 64); R += __shfl_xor(R, 8, 64);
  float anchor = fmaf(0.4f, R, fmaf(0.6f, S[(size_t)node * 8 + hd], Sr06));
  float denom = 1.f;
  float o0 = x0, o1 = x1, o2 = x2, o3 = x3;

  int k0 = off[node], k1 = off[node + 1];
  int k = k0;
  for (; k + 1 < k1; k += 2){
    int sa = csr[k], sb = csr[k + 1];
    ushort4 va = *(const ushort4*)(xlr + (size_t)sa * 512 + c4);
    ushort4 vb = *(const ushort4*)(xlr + (size_t)sb * 512 + c4);
    float Sla = S[(size_t)sa * 8 + hd];
    float Slb = S[(size_t)sb * 8 + hd];
    float xa0 = b2f(va.x), xa1 = b2f(va.y), xa2 = b2f(va.z), xa3 = b2f(va.w);
    float xb0 = b2f(vb.x), xb1 = b2f(vb.y), xb2 = b2f(vb.z), xb3 = b2f(vb.w);
    float Ra = aw0 * fabsf(xa0 + xr0);
    Ra = fmaf(aw1, fabsf(xa1 + xr1), Ra);
    Ra = fmaf(aw2, fabsf(xa2 + xr2), Ra);
    Ra = fmaf(aw3, fabsf(xa3 + xr3), Ra);
    float Rb = aw0 * fabsf(xb0 + xr0);
    Rb = fmaf(aw1, fabsf(xb1 + xr1), Rb);
    Rb = fmaf(aw2, fabsf(xb2 + xr2), Rb);
    Rb = fmaf(aw3, fabsf(xb3 + xr3), Rb);
    Ra += __shfl_xor(Ra, 1, 64); Rb += __shfl_xor(Rb, 1, 64);
    Ra += __shfl_xor(Ra, 2, 64); Rb += __shfl_xor(Rb, 2, 64);
    Ra += __shfl_xor(Ra, 4, 64); Rb += __shfl_xor(Rb, 4, 64);
    Ra += __shfl_xor(Ra, 8, 64); Rb += __shfl_xor(Rb, 8, 64);
    float pa = fmaf(0.4f, Ra, fmaf(0.6f, Sla, Sr06)) - anchor;
    float pb = fmaf(0.4f, Rb, fmaf(0.6f, Slb, Sr06)) - anchor;
    float ea = __expf(pa);
    float eb = __expf(pb);
    denom += ea + eb;
    o0 = fmaf(ea, xa0, fmaf(eb, xb0, o0));
    o1 = fmaf(ea, xa1, fmaf(eb, xb1, o1));
    o2 = fmaf(ea, xa2, fmaf(eb, xb2, o2));
    o3 = fmaf(ea, xa3, fmaf(eb, xb3, o3));
  }
  if (k < k1){
    int s = csr[k];
    ushort4 v = *(const ushort4*)(xlr + (size_t)s * 512 + c4);
    float Sl = S[(size_t)s * 8 + hd];
    x0 = b2f(v.x); x1 = b2f(v.y); x2 = b2f(v.z); x3 = b2f(v.w);
    float Rr = aw0 * fabsf(x0 + xr0);
    Rr = fmaf(aw1, fabsf(x1 + xr1), Rr);
    Rr = fmaf(aw2, fabsf(x2 + xr2), Rr);
    Rr = fmaf(aw3, fabsf(x3 + xr3), Rr);
    Rr += __shfl_xor(Rr, 1, 64); Rr += __shfl_xor(Rr, 2, 64);
    Rr += __shfl_xor(Rr, 4, 64); Rr += __shfl_xor(Rr, 8, 64);
    float p = fmaf(0.4f, Rr, fmaf(0.6f, Sl, Sr06)) - anchor;
    float ep = __expf(p);
    denom += ep;
    o0 = fmaf(ep, x0, o0);
    o1 = fmaf(ep, x1, o1);
    o2 = fmaf(ep, x2, o2);
    o3 = fmaf(ep, x3, o3);
  }
  float inv = 1.f / denom;
  o0 *= inv; o1 *= inv; o2 *= inv; o3 *= inv;
  // mean over 4 heads
  o0 += __shfl_xor(o0, 16, 64); o1 += __shfl_xor(o1, 16, 64);
  o2 += __shfl_xor(o2, 16, 64); o3 += __shfl_xor(o3, 16, 64);
  o0 += __shfl_xor(o0, 32, 64); o1 += __shfl_xor(o1, 32, 64);
  o2 += __shfl_xor(o2, 32, 64); o3 += __shfl_xor(o3, 32, 64);
  int cb = l * 4;
  float g0 = fmaxf(fmaf(o0, 0.25f, bgat[cb + 0]), 0.f);
  float g1 = fmaxf(fmaf(o1, 0.25f, bgat[cb + 1]), 0.f);
  float g2 = fmaxf(fmaf(o2, 0.25f, bgat[cb + 2]), 0.f);
  float g3 = fmaxf(fmaf(o3, 0.25f, bgat[cb + 3]), 0.f);
  float r = g0 * wlin[cb + 0];
  r = fmaf(g1, wlin[cb + 1], r);
  r = fmaf(g2, wlin[cb + 2], r);
  r = fmaf(g3, wlin[cb + 3], r);
  r += __shfl_xor(r, 1, 64); r += __shfl_xor(r, 2, 64);
  r += __shfl_xor(r, 4, 64); r += __shfl_xor(r, 8, 64);
  if (lane == 0) out[node] = r + blin[0];
}

extern "C" void kernel_launch(void* const* d_in, const int* in_sizes, int n_in,
                              void* d_out, int out_size, void* d_ws, size_t ws_size,
                              hipStream_t stream){
  const float* x    = (const float*)d_in[0];
  const int* edge_index = (const int*)d_in[1];
  const float* Wg   = (const float*)d_in[3];
  const float* bgcn = (const float*)d_in[4];
  const float* Wl   = (const float*)d_in[5];
  const float* bl   = (const float*)d_in[6];
  const float* Wr   = (const float*)d_in[7];
  const float* br   = (const float*)d_in[8];
  const float* attw = (const float*)d_in[9];
  const float* bgat = (const float*)d_in[10];
  const float* wlin = (const float*)d_in[11];
  const float* blin = (const float*)d_in[12];
  float* out = (float*)d_out;

  const int N = in_sizes[0] / 128;
  const int E = in_sizes[1] / 2;
  const int* srcv = edge_index;
  const int* dstv = edge_index + E;

  char* w = (char*)d_ws;
  size_t o = 0;
  int* cnt = (int*)(w + o);            o += (((size_t)N * 4) + 255) & ~(size_t)255;
  int* cursor = (int*)(w + o);         o += (((size_t)N * 4) + 255) & ~(size_t)255;
  int* excl = (int*)(w + o);           o += (((size_t)N * 4) + 255) & ~(size_t)255;
  int* off = (int*)(w + o);            o += (((size_t)(N + 1) * 4) + 255) & ~(size_t)255;
  int* bsum = (int*)(w + o);           o += (2048 * 4 + 255) & ~(size_t)255;
  float* dinv = (float*)(w + o);       o += (((size_t)N * 4) + 255) & ~(size_t)255;
  float* S = (float*)(w + o);          o += (((size_t)N * 8 * 4) + 255) & ~(size_t)255;
  unsigned short* xw = (unsigned short*)(w + o);   o += (((size_t)N * 64 * 2) + 255) & ~(size_t)255;
  unsigned short* h = (unsigned short*)(w + o);    o += (((size_t)N * 64 * 2) + 255) & ~(size_t)255;
  unsigned short* xlr = (unsigned short*)(w + o);  o += (((size_t)N * 512 * 2) + 255) & ~(size_t)255;
  int* csr = (int*)(w + o);            o += (((size_t)E * 4) + 255) & ~(size_t)255;
  unsigned short* wp = (unsigned short*)(w + o);   o += (size_t)131072;  // 64x512 x {hi,lo} bf16
  (void)o; (void)ws_size; (void)n_in; (void)out_size;

  const int nbN = (N + 255) / 256;
  const int nbE = (E + 255) / 256;
  const int nb4 = (N + 3) / 4;

  CarbonGNN_36447092474498_init <<<nbN, 256, 0, stream>>>(cnt, cursor, N);
  CarbonGNN_36447092474498_hist <<<nbE, 256, 0, stream>>>(dstv, E, cnt);
  CarbonGNN_36447092474498_scan1<<<nbN, 256, 0, stream>>>(cnt, N, excl, bsum);
  CarbonGNN_36447092474498_scan3<<<nbN, 256, 0, stream>>>(excl, bsum, nbN, cnt, N, E, off, dinv);
  CarbonGNN_36447092474498_fill <<<nbE, 256, 0, stream>>>(srcv, dstv, E, off, cursor, csr);
  CarbonGNN_36447092474498_gemm1<<<nb4, 256, 0, stream>>>(x, Wg, xw, N);
  CarbonGNN_36447092474498_gcn  <<<nb4, 256, 0, stream>>>(xw, off, csr, dinv, bgcn, h, N);
  CarbonGNN_36447092474498_wpack<<<256, 256, 0, stream>>>(Wl, Wr, wp);
  dim3 g2((N + 127) / 128, 2);
  CarbonGNN_36447092474498_gemm2<<<g2, 256, 0, stream>>>(h, wp, bl, br, attw, xlr, S, N);
  CarbonGNN_36447092474498_kernel<<<nb4, 256, 0, stream>>>(xlr, off, csr, attw, S, bgat, wlin, blin, out, N);
}

// Round 2
// 314.148 us; speedup vs baseline: 1.3313x; 1.2223x over previous
//
#include <hip/hip_runtime.h>

static __device__ inline float b2f(unsigned short u){
  union { unsigned int i; float f; } v; v.i = ((unsigned int)u) << 16; return v.f;
}
static __device__ inline unsigned short f2b(float f){
  union { float ff; unsigned int u; } v; v.ff = f;
  unsigned int xx = v.u;
  return (unsigned short)((xx + 0x7fffu + ((xx >> 16) & 1u)) >> 16);
}

typedef __attribute__((ext_vector_type(8))) short short8x;   // 8 bf16 (4 VGPRs)
typedef __attribute__((ext_vector_type(4))) float f32x4;

// unpack 8 bf16 (as uint4) -> 8 floats
static __device__ inline void bf8up(uint4 v, float* f){
  union { unsigned int u; float ff; } t;
  t.u = v.x << 16;          f[0] = t.ff;
  t.u = v.x & 0xffff0000u;  f[1] = t.ff;
  t.u = v.y << 16;          f[2] = t.ff;
  t.u = v.y & 0xffff0000u;  f[3] = t.ff;
  t.u = v.z << 16;          f[4] = t.ff;
  t.u = v.z & 0xffff0000u;  f[5] = t.ff;
  t.u = v.w << 16;          f[6] = t.ff;
  t.u = v.w & 0xffff0000u;  f[7] = t.ff;
}

// fp32 inputs/output (verified r13); internal staging bf16 (verified 4.9e-4).

__global__ __launch_bounds__(256) void CarbonGNN_36447092474498_init(
    int* __restrict__ cnt, int* __restrict__ cursor, int N){
  int i = blockIdx.x * 256 + threadIdx.x;
  if (i < N){ cnt[i] = 0; cursor[i] = 0; }
}

__global__ __launch_bounds__(256) void CarbonGNN_36447092474498_hist(
    const int* __restrict__ dst, int E, int* __restrict__ cnt){
  int e = blockIdx.x * 256 + threadIdx.x;
  if (e < E) atomicAdd(&cnt[dst[e]], 1);
}

__global__ __launch_bounds__(256) void CarbonGNN_36447092474498_scan1(
    const int* __restrict__ cnt, int n, int* __restrict__ excl, int* __restrict__ bsum){
  __shared__ int sm[256];
  int t = threadIdx.x;
  int i = blockIdx.x * 256 + t;
  int v = (i < n) ? cnt[i] : 0;
  sm[t] = v;
  __syncthreads();
  for (int ofs = 1; ofs < 256; ofs <<= 1){
    int y = (t >= ofs) ? sm[t - ofs] : 0;
    __syncthreads();
    sm[t] += y;
    __syncthreads();
  }
  if (i < n) excl[i] = sm[t] - v;
  if (t == 255) bsum[blockIdx.x] = sm[t];
}

// scan2 merged in: every block redundantly scans the <=256 block sums.
__global__ __launch_bounds__(256) void CarbonGNN_36447092474498_scan3(
    const int* __restrict__ excl, const int* __restrict__ bsum, int nb,
    const int* __restrict__ cnt, int n, int E,
    int* __restrict__ off, float* __restrict__ dinv){
  __shared__ int sm[256];
  int t = threadIdx.x;
  int v = (t < nb) ? bsum[t] : 0;
  sm[t] = v;
  __syncthreads();
  for (int ofs = 1; ofs < 256; ofs <<= 1){
    int y = (t >= ofs) ? sm[t - ofs] : 0;
    __syncthreads();
    sm[t] += y;
    __syncthreads();
  }
  int bofs = (blockIdx.x == 0) ? 0 : sm[blockIdx.x - 1];
  int i = blockIdx.x * 256 + t;
  if (i < n){
    off[i] = excl[i] + bofs;
    int c = cnt[i];
    dinv[i] = (c >= 0 && c <= E) ? rsqrtf((float)(c + 1)) : 1.0f;
  }
  if (i == 0) off[n] = E;
}

__global__ __launch_bounds__(256) void CarbonGNN_36447092474498_fill(
    const int* __restrict__ src, const int* __restrict__ dst, int E,
    const int* __restrict__ off, int* __restrict__ cursor, int* __restrict__ csr){
  int e = blockIdx.x * 256 + threadIdx.x;
  if (e < E){
    int d = dst[e];
    int p = atomicAdd(&cursor[d], 1);
    csr[off[d] + p] = src[e];
  }
}

// Pre-pack Wg^T [64 x 128] into MFMA A-fragment lane order, hi+lo bf16 split.
// fb = ct*8 + kt*2 + p (ct=col-tile of 16 over 64 cols, kt=K-tile of 32 over
// 128, p=0 hi / p=1 lo); elem fb*512 + lane*8 + i holds
// bf16part( Wg[k = kt*32 + (lane>>4)*8 + i][c = ct*16 + (lane&15)] ).
__global__ __launch_bounds__(256) void CarbonGNN_36447092474498_wpack1(
    const float* __restrict__ Wg, unsigned short* __restrict__ wp1){
  int idx = blockIdx.x * 256 + threadIdx.x;       // 0..16383
  int i    = idx & 7;
  int lane = (idx >> 3) & 63;
  int p    = (idx >> 9) & 1;
  int kt   = (idx >> 10) & 3;
  int ct   = idx >> 12;                            // 0..3
  int c = ct * 16 + (lane & 15);
  int k = kt * 32 + (lane >> 4) * 8 + i;
  float w = Wg[k * 64 + c];
  unsigned short hi = f2b(w);
  unsigned short outv = p ? f2b(w - b2f(hi)) : hi;
  int fb = ct * 8 + kt * 2 + p;
  wp1[(size_t)fb * 512 + lane * 8 + i] = outv;
}

// gemm1 (MFMA): xw[N,64] = x[N,128] @ Wg[128,64], bf16 out.
// Transposed product D' = Wg^T . x^T, 16x16x32 bf16 MFMA; x converted to
// bf16 hi+lo in-register (3 MFMA per (ct,kt): wh*xh + wl*xh + wh*xl keeps
// ~fp32 precision). Wave = 16 nodes; block = 4 waves = 64 nodes; no LDS.
__global__ __launch_bounds__(256) void CarbonGNN_36447092474498_gemm1(
    const float* __restrict__ x, const unsigned short* __restrict__ wp1,
    unsigned short* __restrict__ xw, int N){
  int t = threadIdx.x;
  int lane = t & 63;
  int l15 = lane & 15;
  int lg = lane >> 4;
  int row = blockIdx.x * 64 + (t >> 6) * 16 + l15;
  int rc = row < N ? row : N - 1;
  const float* xp = x + (size_t)rc * 128 + lg * 8;

  short8x xh[4], xlo[4];
  #pragma unroll
  for (int kt = 0; kt < 4; kt++){
    float4 a = *(const float4*)(xp + kt * 32);
    float4 b = *(const float4*)(xp + kt * 32 + 4);
    unsigned int h0, h1, h2, h3;
    asm("v_cvt_pk_bf16_f32 %0, %1, %2" : "=v"(h0) : "v"(a.x), "v"(a.y));
    asm("v_cvt_pk_bf16_f32 %0, %1, %2" : "=v"(h1) : "v"(a.z), "v"(a.w));
    asm("v_cvt_pk_bf16_f32 %0, %1, %2" : "=v"(h2) : "v"(b.x), "v"(b.y));
    asm("v_cvt_pk_bf16_f32 %0, %1, %2" : "=v"(h3) : "v"(b.z), "v"(b.w));
    union { unsigned int u[4]; short8x v; } H;
    H.u[0] = h0; H.u[1] = h1; H.u[2] = h2; H.u[3] = h3;
    xh[kt] = H.v;
    union { unsigned int u; float ff; } q;
    float r0, r1, r2, r3, r4, r5, r6, r7;
    q.u = h0 << 16;          r0 = a.x - q.ff;
    q.u = h0 & 0xffff0000u;  r1 = a.y - q.ff;
    q.u = h1 << 16;          r2 = a.z - q.ff;
    q.u = h1 & 0xffff0000u;  r3 = a.w - q.ff;
    q.u = h2 << 16;          r4 = b.x - q.ff;
    q.u = h2 & 0xffff0000u;  r5 = b.y - q.ff;
    q.u = h3 << 16;          r6 = b.z - q.ff;
    q.u = h3 & 0xffff0000u;  r7 = b.w - q.ff;
    unsigned int l0, l1, l2, l3;
    asm("v_cvt_pk_bf16_f32 %0, %1, %2" : "=v"(l0) : "v"(r0), "v"(r1));
    asm("v_cvt_pk_bf16_f32 %0, %1, %2" : "=v"(l1) : "v"(r2), "v"(r3));
    asm("v_cvt_pk_bf16_f32 %0, %1, %2" : "=v"(l2) : "v"(r4), "v"(r5));
    asm("v_cvt_pk_bf16_f32 %0, %1, %2" : "=v"(l3) : "v"(r6), "v"(r7));
    union { unsigned int u[4]; short8x v; } L;
    L.u[0] = l0; L.u[1] = l1; L.u[2] = l2; L.u[3] = l3;
    xlo[kt] = L.v;
  }

  #pragma unroll
  for (int ct = 0; ct < 4; ct++){
    f32x4 acc = {0.f, 0.f, 0.f, 0.f};
    #pragma unroll
    for (int kt = 0; kt < 4; kt++){
      const unsigned short* ap = wp1 + (size_t)(ct * 8 + kt * 2) * 512 + (size_t)lane * 8;
      short8x wh = *(const short8x*)(ap);
      short8x wl = *(const short8x*)(ap + 512);
      acc = __builtin_amdgcn_mfma_f32_16x16x32_bf16(wh, xh[kt], acc, 0, 0, 0);
      acc = __builtin_amdgcn_mfma_f32_16x16x32_bf16(wl, xh[kt], acc, 0, 0, 0);
      acc = __builtin_amdgcn_mfma_f32_16x16x32_bf16(wh, xlo[kt], acc, 0, 0, 0);
    }
    unsigned int p01, p23;
    asm("v_cvt_pk_bf16_f32 %0, %1, %2" : "=v"(p01) : "v"(acc[0]), "v"(acc[1]));
    asm("v_cvt_pk_bf16_f32 %0, %1, %2" : "=v"(p23) : "v"(acc[2]), "v"(acc[3]));
    if (row < N){
      uint2 pv; pv.x = p01; pv.y = p23;
      *(uint2*)(xw + (size_t)row * 64 + ct * 16 + lg * 4) = pv;
    }
  }
}

// GCN aggregate: quarter-wave per edge — 16 lanes x 4 channels (8B loads),
// 4 edges per instruction stream; combine quarters with 2 shfl at the end.
__global__ __launch_bounds__(256) void CarbonGNN_36447092474498_gcn(
    const unsigned short* __restrict__ xw, const int* __restrict__ off,
    const int* __restrict__ csr, const float* __restrict__ dinv,
    const float* __restrict__ bgcn, unsigned short* __restrict__ h, int N){
  int node = blockIdx.x * 4 + (threadIdx.x >> 6);
  if (node >= N) return;
  int lane = threadIdx.x & 63;
  int q = lane >> 4;           // edge slot 0..3
  int j = lane & 15;           // channel group
  int c4 = j * 4;
  float di = dinv[node];
  float o0 = 0.f, o1 = 0.f, o2 = 0.f, o3 = 0.f;
  int k0 = off[node], k1 = off[node + 1];
  int k = k0;
  for (; k + 7 < k1; k += 8){            // 8 edges per iter (2 per quarter)
    int sa = csr[k + q];
    int sb = csr[k + 4 + q];
    ushort4 va = *(const ushort4*)(xw + (size_t)sa * 64 + c4);
    ushort4 vb = *(const ushort4*)(xw + (size_t)sb * 64 + c4);
    float da = dinv[sa], db = dinv[sb];
    o0 = fmaf(b2f(va.x), da, o0); o1 = fmaf(b2f(va.y), da, o1);
    o2 = fmaf(b2f(va.z), da, o2); o3 = fmaf(b2f(va.w), da, o3);
    o0 = fmaf(b2f(vb.x), db, o0); o1 = fmaf(b2f(vb.y), db, o1);
    o2 = fmaf(b2f(vb.z), db, o2); o3 = fmaf(b2f(vb.w), db, o3);
  }
  for (; k < k1; k += 4){                // masked tail, 4 edges per iter
    int kk = k + q;
    bool act = kk < k1;
    int s = csr[act ? kk : k0];
    ushort4 v = *(const ushort4*)(xw + (size_t)s * 64 + c4);
    float d = act ? dinv[s] : 0.f;
    o0 = fmaf(b2f(v.x), d, o0); o1 = fmaf(b2f(v.y), d, o1);
    o2 = fmaf(b2f(v.z), d, o2); o3 = fmaf(b2f(v.w), d, o3);
  }
  // combine the 4 quarters
  o0 += __shfl_xor(o0, 16, 64); o1 += __shfl_xor(o1, 16, 64);
  o2 += __shfl_xor(o2, 16, 64); o3 += __shfl_xor(o3, 16, 64);
  o0 += __shfl_xor(o0, 32, 64); o1 += __shfl_xor(o1, 32, 64);
  o2 += __shfl_xor(o2, 32, 64); o3 += __shfl_xor(o3, 32, 64);
  // self + bias + relu; quarter 0 writes
  ushort4 sv = *(const ushort4*)(xw + (size_t)node * 64 + c4);
  float4 bg = *(const float4*)(bgcn + c4);
  float t0 = fmaf(b2f(sv.x), di, o0);
  float t1 = fmaf(b2f(sv.y), di, o1);
  float t2 = fmaf(b2f(sv.z), di, o2);
  float t3 = fmaf(b2f(sv.w), di, o3);
  float v0 = fmaxf(fmaf(t0, di, bg.x), 0.f);
  float v1 = fmaxf(fmaf(t1, di, bg.y), 0.f);
  float v2 = fmaxf(fmaf(t2, di, bg.z), 0.f);
  float v3 = fmaxf(fmaf(t3, di, bg.w), 0.f);
  if (q == 0){
    ushort4 hv;
    hv.x = f2b(v0); hv.y = f2b(v1); hv.z = f2b(v2); hv.w = f2b(v3);
    *(ushort4*)(h + (size_t)node * 64 + c4) = hv;
  }
}

// Pre-pack W^T = [Wl|Wr]^T into MFMA A-fragment lane order, split into
// bf16 hi + bf16 lo (residual) so h @ (hi+lo) keeps ~fp32 weight precision.
__global__ __launch_bounds__(256) void CarbonGNN_36447092474498_wpack(
    const float* __restrict__ Wl, const float* __restrict__ Wr,
    unsigned short* __restrict__ wp){
  int idx = blockIdx.x * 256 + threadIdx.x;       // 0..65535
  int i    = idx & 7;
  int lane = (idx >> 3) & 63;
  int p    = (idx >> 9) & 1;
  int kt   = (idx >> 10) & 1;
  int ct   = idx >> 11;                            // 0..31
  int c = ct * 16 + (lane & 15);
  int k = kt * 32 + (lane >> 4) * 8 + i;
  float w = (c < 256) ? Wl[k * 256 + c] : Wr[k * 256 + (c - 256)];
  unsigned short hi = f2b(w);
  unsigned short out = p ? f2b(w - b2f(hi)) : hi;
  int fb = ct * 4 + kt * 2 + p;
  wp[(size_t)fb * 512 + lane * 8 + i] = out;
}

// gemm2 (MFMA): xlr[N,512] = h[N,64] @ [Wl|Wr][64,512] + b, bf16 out, plus
// S[n][side*4+head] = att_head . rounded(x_side[n, head*64 .. +63]).
__global__ __launch_bounds__(256) void CarbonGNN_36447092474498_gemm2(
    const unsigned short* __restrict__ h, const unsigned short* __restrict__ wp,
    const float* __restrict__ bl, const float* __restrict__ br,
    const float* __restrict__ attw,
    unsigned short* __restrict__ xlr, float* __restrict__ S, int N){
  int t = threadIdx.x;
  int lane = t & 63;
  int l15 = lane & 15;
  int lg = lane >> 4;
  int r0 = blockIdx.x * 128 + (t >> 6) * 32;
  int side = blockIdx.y;                 // 0: xl cols 0..255, 1: xr cols 256..511

  short8x bfr[2][2];
  #pragma unroll
  for (int rt = 0; rt < 2; rt++){
    int row = r0 + rt * 16 + l15;
    int rc = row < N ? row : (N - 1);
    const unsigned short* hp = h + (size_t)rc * 64 + lg * 8;
    bfr[rt][0] = *(const short8x*)(hp);
    bfr[rt][1] = *(const short8x*)(hp + 32);
  }

  const unsigned short* wpp = wp + (size_t)(side * 16) * 2048 + (size_t)lane * 8;
  short8x ah0 = *(const short8x*)(wpp);
  short8x al0 = *(const short8x*)(wpp + 512);
  short8x ah1 = *(const short8x*)(wpp + 1024);
  short8x al1 = *(const short8x*)(wpp + 1536);

  float sp0 = 0.f, sp1 = 0.f;           // S partials per row-tile
  for (int cl = 0; cl < 16; cl++){
    short8x ch0 = ah0, cg0 = al0, ch1 = ah1, cg1 = al1;
    if (cl < 15){
      const unsigned short* np = wpp + (size_t)(cl + 1) * 2048;
      ah0 = *(const short8x*)(np);
      al0 = *(const short8x*)(np + 512);
      ah1 = *(const short8x*)(np + 1024);
      al1 = *(const short8x*)(np + 1536);
    }
    int c4 = (side * 16 + cl) * 16 + lg * 4;   // first of this lane's 4 out cols
    float4 bias = (c4 < 256) ? *(const float4*)(bl + c4)
                             : *(const float4*)(br + (c4 - 256));
    float4 aw = *(const float4*)(attw + (c4 & 255));
    #pragma unroll
    for (int rt = 0; rt < 2; rt++){
      f32x4 acc = {0.f, 0.f, 0.f, 0.f};
      acc = __builtin_amdgcn_mfma_f32_16x16x32_bf16(ch0, bfr[rt][0], acc, 0, 0, 0);
      acc = __builtin_amdgcn_mfma_f32_16x16x32_bf16(cg0, bfr[rt][0], acc, 0, 0, 0);
      acc = __builtin_amdgcn_mfma_f32_16x16x32_bf16(ch1, bfr[rt][1], acc, 0, 0, 0);
      acc = __builtin_amdgcn_mfma_f32_16x16x32_bf16(cg1, bfr[rt][1], acc, 0, 0, 0);
      float v0 = acc[0] + bias.x;
      float v1 = acc[1] + bias.y;
      float v2 = acc[2] + bias.z;
      float v3 = acc[3] + bias.w;
      unsigned int p01, p23;                    // RNE pack, matches f2b
      asm("v_cvt_pk_bf16_f32 %0, %1, %2" : "=v"(p01) : "v"(v0), "v"(v1));
      asm("v_cvt_pk_bf16_f32 %0, %1, %2" : "=v"(p23) : "v"(v2), "v"(v3));
      int row = r0 + rt * 16 + l15;
      if (row < N){
        uint2 pv; pv.x = p01; pv.y = p23;
        *(uint2*)(xlr + (size_t)row * 512 + c4) = pv;
      }
      union { unsigned int u; float f; } q0, q1, q2, q3;
      q0.u = p01 << 16; q1.u = p01 & 0xffff0000u;
      q2.u = p23 << 16; q3.u = p23 & 0xffff0000u;
      float s = fmaf(aw.x, q0.f, fmaf(aw.y, q1.f, fmaf(aw.z, q2.f, aw.w * q3.f)));
      if (rt == 0) sp0 += s; else sp1 += s;
    }
    if ((cl & 3) == 3){                          // head boundary (64 cols)
      int head = cl >> 2;
      float s0 = sp0, s1 = sp1;
      s0 += __shfl_xor(s0, 16, 64); s0 += __shfl_xor(s0, 32, 64);
      s1 += __shfl_xor(s1, 16, 64); s1 += __shfl_xor(s1, 32, 64);
      if (lane < 16){
        int ra = r0 + l15;
        if (ra < N) S[(size_t)ra * 8 + side * 4 + head] = s0;
        int rb = r0 + 16 + l15;
        if (rb < N) S[(size_t)rb * 8 + side * 4 + head] = s1;
      }
      sp0 = 0.f; sp1 = 0.f;
    }
  }
}

// GATv2: anchored-softmax (anchor = self logit), lrelu decomposed via S.
// Half-wave per edge: 32 lanes x 8 cols (16B loads); 2 edges share one
// instruction stream; 4 edges in flight in the main loop.
// Lane map: half = lane>>5 (edge parity), j = lane&31, head = j>>3,
// cols c8 = j*8 (covers all 256 xl cols).
__global__ __launch_bounds__(256) void CarbonGNN_36447092474498_kernel(
    const unsigned short* __restrict__ xlr, const int* __restrict__ off,
    const int* __restrict__ csr, const float* __restrict__ attw,
    const float* __restrict__ S,
    const float* __restrict__ bgat, const float* __restrict__ wlin,
    const float* __restrict__ blin, float* __restrict__ out, int N){
  int node = blockIdx.x * 4 + (threadIdx.x >> 6);
  if (node >= N) return;
  int lane = threadIdx.x & 63;
  int half = lane >> 5;
  int j = lane & 31;
  int hd = j >> 3;
  int c8 = j * 8;
  const unsigned short* xrow = xlr + (size_t)node * 512;

  float xr[8], aw[8];
  bf8up(*(const uint4*)(xrow + 256 + c8), xr);
  {
    float4 a0 = *(const float4*)(attw + c8);
    float4 a1 = *(const float4*)(attw + c8 + 4);
    aw[0] = a0.x; aw[1] = a0.y; aw[2] = a0.z; aw[3] = a0.w;
    aw[4] = a1.x; aw[5] = a1.y; aw[6] = a1.z; aw[7] = a1.w;
  }
  float Sr06 = 0.6f * S[(size_t)node * 8 + 4 + hd];

  // self edge: anchor
  float xs[8];
  bf8up(*(const uint4*)(xrow + c8), xs);
  float R = aw[0] * fabsf(xs[0] + xr[0]);
  #pragma unroll
  for (int i = 1; i < 8; i++) R = fmaf(aw[i], fabsf(xs[i] + xr[i]), R);
  R += __shfl_xor(R, 1, 64); R += __shfl_xor(R, 2, 64); R += __shfl_xor(R, 4, 64);
  float anchor = fmaf(0.4f, R, fmaf(0.6f, S[(size_t)node * 8 + hd], Sr06));

  float o[8];
  float denom;
  if (half == 0){
    denom = 1.f;
    #pragma unroll
    for (int i = 0; i < 8; i++) o[i] = xs[i];
  } else {
    denom = 0.f;
    #pragma unroll
    for (int i = 0; i < 8; i++) o[i] = 0.f;
  }

  int k0 = off[node], k1 = off[node + 1];
  int k = k0;
  for (; k + 3 < k1; k += 4){            // 4 edges per iter, 2 per half
    int s0 = csr[k + half];
    int s1 = csr[k + 2 + half];
    uint4 v0 = *(const uint4*)(xlr + (size_t)s0 * 512 + c8);
    uint4 v1 = *(const uint4*)(xlr + (size_t)s1 * 512 + c8);
    float Sl0 = S[(size_t)s0 * 8 + hd];
    float Sl1 = S[(size_t)s1 * 8 + hd];
    float xa[8], xb[8];
    bf8up(v0, xa);
    bf8up(v1, xb);
    float Ra = aw[0] * fabsf(xa[0] + xr[0]);
    float Rb = aw[0] * fabsf(xb[0] + xr[0]);
    #pragma unroll
    for (int i = 1; i < 8; i++){
      Ra = fmaf(aw[i], fabsf(xa[i] + xr[i]), Ra);
      Rb = fmaf(aw[i], fabsf(xb[i] + xr[i]), Rb);
    }
    Ra += __shfl_xor(Ra, 1, 64); Rb += __shfl_xor(Rb, 1, 64);
    Ra += __shfl_xor(Ra, 2, 64); Rb += __shfl_xor(Rb, 2, 64);
    Ra += __shfl_xor(Ra, 4, 64); Rb += __shfl_xor(Rb, 4, 64);
    float pa = fmaf(0.4f, Ra, fmaf(0.6f, Sl0, Sr06)) - anchor;
    float pb = fmaf(0.4f, Rb, fmaf(0.6f, Sl1, Sr06)) - anchor;
    float ea = __expf(pa);
    float eb = __expf(pb);
    denom += ea + eb;
    #pragma unroll
    for (int i = 0; i < 8; i++) o[i] = fmaf(ea, xa[i], fmaf(eb, xb[i], o[i]));
  }
  for (; k < k1; k += 2){                // masked tail, 2 edges per iter
    int kk = k + half;
    bool act = kk < k1;
    int s = csr[act ? kk : k0];
    uint4 v = *(const uint4*)(xlr + (size_t)s * 512 + c8);
    float Sl = S[(size_t)s * 8 + hd];
    float xa[8];
    bf8up(v, xa);
    float Ra = aw[0] * fabsf(xa[0] + xr[0]);
    #pragma unroll
    for (int i = 1; i < 8; i++) Ra = fmaf(aw[i], fabsf(xa[i] + xr[i]), Ra);
    Ra += __shfl_xor(Ra, 1, 64); Ra += __shfl_xor(Ra, 2, 64); Ra += __shfl_xor(Ra, 4, 64);
    float pa = fmaf(0.4f, Ra, fmaf(0.6f, Sl, Sr06)) - anchor;
    float ea = act ? __expf(pa) : 0.f;
    denom += ea;
    #pragma unroll
    for (int i = 0; i < 8; i++) o[i] = fmaf(ea, xa[i], o[i]);
  }

  // combine halves
  denom += __shfl_xor(denom, 32, 64);
  #pragma unroll
  for (int i = 0; i < 8; i++) o[i] += __shfl_xor(o[i], 32, 64);
  float inv = 1.f / denom;
  #pragma unroll
  for (int i = 0; i < 8; i++) o[i] *= inv;
  // mean over 4 heads (head groups = lane bits 3-4)
  #pragma unroll
  for (int i = 0; i < 8; i++){
    o[i] += __shfl_xor(o[i], 8, 64);
    o[i] += __shfl_xor(o[i], 16, 64);
  }
  int cb = (j & 7) * 8;                  // 8 channels per lane, g=0..7 cover 64
  float4 bg0 = *(const float4*)(bgat + cb);
  float4 bg1 = *(const float4*)(bgat + cb + 4);
  float4 wl0 = *(const float4*)(wlin + cb);
  float4 wl1 = *(const float4*)(wlin + cb + 4);
  float bgv[8] = {bg0.x, bg0.y, bg0.z, bg0.w, bg1.x, bg1.y, bg1.z, bg1.w};
  float wlv[8] = {wl0.x, wl0.y, wl0.z, wl0.w, wl1.x, wl1.y, wl1.z, wl1.w};
  float r = 0.f;
  #pragma unroll
  for (int i = 0; i < 8; i++){
    float g = fmaxf(fmaf(o[i], 0.25f, bgv[i]), 0.f);
    r = fmaf(g, wlv[i], r);
  }
  r += __shfl_xor(r, 1, 64); r += __shfl_xor(r, 2, 64); r += __shfl_xor(r, 4, 64);
  if (lane == 0) out[node] = r + blin[0];
}

extern "C" void kernel_launch(void* const* d_in, const int* in_sizes, int n_in,
                              void* d_out, int out_size, void* d_ws, size_t ws_size,
                              hipStream_t stream){
  const float* x    = (const float*)d_in[0];
  const int* edge_index = (const int*)d_in[1];
  const float* Wg   = (const float*)d_in[3];
  const float* bgcn = (const float*)d_in[4];
  const float* Wl   = (const float*)d_in[5];
  const float* bl   = (const float*)d_in[6];
  const float* Wr   = (const float*)d_in[7];
  const float* br   = (const float*)d_in[8];
  const float* attw = (const float*)d_in[9];
  const float* bgat = (const float*)d_in[10];
  const float* wlin = (const float*)d_in[11];
  const float* blin = (const float*)d_in[12];
  float* out = (float*)d_out;

  const int N = in_sizes[0] / 128;
  const int E = in_sizes[1] / 2;
  const int* srcv = edge_index;
  const int* dstv = edge_index + E;

  char* w = (char*)d_ws;
  size_t o = 0;
  int* cnt = (int*)(w + o);            o += (((size_t)N * 4) + 255) & ~(size_t)255;
  int* cursor = (int*)(w + o);         o += (((size_t)N * 4) + 255) & ~(size_t)255;
  int* excl = (int*)(w + o);           o += (((size_t)N * 4) + 255) & ~(size_t)255;
  int* off = (int*)(w + o);            o += (((size_t)(N + 1) * 4) + 255) & ~(size_t)255;
  int* bsum = (int*)(w + o);           o += (2048 * 4 + 255) & ~(size_t)255;
  float* dinv = (float*)(w + o);       o += (((size_t)N * 4) + 255) & ~(size_t)255;
  float* S = (float*)(w + o);          o += (((size_t)N * 8 * 4) + 255) & ~(size_t)255;
  unsigned short* xw = (unsigned short*)(w + o);   o += (((size_t)N * 64 * 2) + 255) & ~(size_t)255;
  unsigned short* h = (unsigned short*)(w + o);    o += (((size_t)N * 64 * 2) + 255) & ~(size_t)255;
  unsigned short* xlr = (unsigned short*)(w + o);  o += (((size_t)N * 512 * 2) + 255) & ~(size_t)255;
  int* csr = (int*)(w + o);            o += (((size_t)E * 4) + 255) & ~(size_t)255;
  unsigned short* wp = (unsigned short*)(w + o);   o += (size_t)131072;  // 64x512 x {hi,lo} bf16
  unsigned short* wp1 = (unsigned short*)(w + o);  o += (size_t)32768;   // 128x64 x {hi,lo} bf16
  (void)o; (void)ws_size; (void)n_in; (void)out_size;

  const int nbN = (N + 255) / 256;
  const int nbE = (E + 255) / 256;
  const int nb4 = (N + 3) / 4;

  CarbonGNN_36447092474498_init <<<nbN, 256, 0, stream>>>(cnt, cursor, N);
  CarbonGNN_36447092474498_hist <<<nbE, 256, 0, stream>>>(dstv, E, cnt);
  CarbonGNN_36447092474498_scan1<<<nbN, 256, 0, stream>>>(cnt, N, excl, bsum);
  CarbonGNN_36447092474498_scan3<<<nbN, 256, 0, stream>>>(excl, bsum, nbN, cnt, N, E, off, dinv);
  CarbonGNN_36447092474498_fill <<<nbE, 256, 0, stream>>>(srcv, dstv, E, off, cursor, csr);
  CarbonGNN_36447092474498_wpack1<<<64, 256, 0, stream>>>(Wg, wp1);
  CarbonGNN_36447092474498_gemm1<<<(N + 63) / 64, 256, 0, stream>>>(x, wp1, xw, N);
  CarbonGNN_36447092474498_gcn  <<<nb4, 256, 0, stream>>>(xw, off, csr, dinv, bgcn, h, N);
  CarbonGNN_36447092474498_wpack<<<256, 256, 0, stream>>>(Wl, Wr, wp);
  dim3 g2((N + 127) / 128, 2);
  CarbonGNN_36447092474498_gemm2<<<g2, 256, 0, stream>>>(h, wp, bl, br, attw, xlr, S, N);
  CarbonGNN_36447092474498_kernel<<<nb4, 256, 0, stream>>>(xlr, off, csr, attw, S, bgat, wlin, blin, out, N);
}